// Round 1
// baseline (151973.169 us; speedup 1.0000x reference)
//
#include <hip/hip_runtime.h>
#include <cstdint>
#include <cstddef>

// Problem constants
#define TT 512
#define BB 64
#define DIN0 256
#define HH 512
#define NWG 256

// Workspace layout (float offsets)
#define OFF_H0OUT 0ul
#define LEN_H0OUT (512ul*1024ul*64ul)            /* layer0 output, (T,1024,B) */
#define OFF_OUT   (OFF_H0OUT + LEN_H0OUT)
#define LEN_OUT   (512ul*512ul*64ul)             /* layer1 fwd+bwd sum, (T,512,B) */
#define OFF_HBUF  (OFF_OUT + LEN_OUT)
#define LEN_HBUF  (2ul*2ul*2ul*512ul*64ul)       /* [layer][pingpong][dir][j][b] */
#define OFF_CTR   (OFF_HBUF + LEN_HBUF)
#define LEN_CTR   1024ul                          /* [layer][step] step counters */
#define OFF_E     (OFF_CTR + LEN_CTR)
#define LEN_E     (64ul*512ul)                    /* attention logits (B,T) */
#define OFF_AT    (OFF_E + LEN_E)
#define LEN_AT    (512ul*64ul)                    /* softmax weights (T,B) */
#define OFF_POOL  (OFF_AT + LEN_AT)
#define LEN_POOL  (512ul*64ul)                    /* pooled (512,B) */

__device__ __forceinline__ void wait_ctr(const unsigned* p, unsigned target) {
  if (threadIdx.x == 0) {
    while (__hip_atomic_load(p, __ATOMIC_ACQUIRE, __HIP_MEMORY_SCOPE_AGENT) < target)
      __builtin_amdgcn_s_sleep(1);
  }
  __syncthreads();
}

// Persistent cooperative kernel: both biLSTM layers.
// 256 wgs x 256 thr. wg -> (dir = wg>>7, jbase = (wg&127)*4): 4 h-columns, 16 gate rows.
// Compute map: gq = tid&3 (gate), bq = tid>>2 (batch).  Epilogue map: b2 = tid&63, jj2 = tid>>6.
__global__ void __launch_bounds__(256) lstm_coop(
    const float* __restrict__ x,
    const float* __restrict__ Wih0, const float* __restrict__ Whh0, const float* __restrict__ b0,
    const float* __restrict__ Wih1, const float* __restrict__ Whh1, const float* __restrict__ b1,
    float* __restrict__ ws)
{
  float* h0out  = ws + OFF_H0OUT;
  float* outsum = ws + OFF_OUT;
  float* hbuf   = ws + OFF_HBUF;
  unsigned* ctr = (unsigned*)(ws + OFF_CTR);

  __shared__ float xh[64*132];   // staged [b][k] chunk, stride 132 (16B aligned)
  __shared__ float pre[16*64];   // gate preacts [gate*4+jj][b]
  __shared__ float cst[256];     // cell state [jj][b] for this wg's 4 columns

  const int tid = threadIdx.x;
  const int wg  = blockIdx.x;
  const int d     = wg >> 7;
  const int jbase = (wg & 127) << 2;

  const int gq = tid & 3;
  const int bq = tid >> 2;
  const int b2  = tid & 63;
  const int jj2 = tid >> 6;

  for (int layer = 0; layer < 2; ++layer) {
    const int DinL = layer ? 1024 : DIN0;
    const int nchunk = (DinL + HH) >> 7;              // 6 or 12 chunks of 128
    const float* Wih  = layer ? Wih1 : Wih0;
    const float* Whh  = layer ? Whh1 : Whh0;
    const float* bias = layer ? b1 : b0;
    const float* xb   = layer ? h0out : x;            // layer1 x-source is (T,1024,B)
    float* hb = hbuf + (size_t)layer * 131072;        // 2 pingpong x 2 dir x 512 x 64

    if (layer == 1) wait_ctr(&ctr[511], NWG);         // layer0 fully done (acquire)
    cst[tid] = 0.0f;
    const float4 brow = *(const float4*)(bias + d*2048 + gq*512 + jbase);
    __syncthreads();

    for (int s = 0; s < TT; ++s) {
      const int t_in = d ? (TT - 1 - s) : s;
      if (s > 0) wait_ctr(&ctr[layer*512 + s - 1], NWG);
      const int cur = s & 1;
      const float* hin = hb + (cur*2 + d)*32768;

      float acc0 = brow.x, acc1 = brow.y, acc2 = brow.z, acc3 = brow.w;

      for (int ch = 0; ch < nchunk; ++ch) {
        const int kc = ch << 7;
        __syncthreads();                               // protect xh (WAR)
        if (layer == 0 && ch < 2) {
          // pattern A: input is (T,B,256), k-major rows
          const float* xr = x + ((size_t)t_in*64 + (size_t)(tid>>2))*256 + kc + (tid&3)*32;
          float* dst = xh + (tid>>2)*132 + (tid&3)*32;
          #pragma unroll
          for (int i = 0; i < 8; ++i)
            *(float4*)(dst + i*4) = *(const float4*)(xr + i*4);
        } else {
          // pattern B: source is [k][b] (h0out slice or hidden pingpong)
          const float* src = (kc < DinL) ? (xb + ((size_t)t_in*DinL + kc)*64)
                                         : (hin + (size_t)(kc - DinL)*64);
          const int bl = tid & 63, kq = tid >> 6;
          float* dst = xh + bl*132;
          #pragma unroll
          for (int p = 0; p < 8; ++p) {
            const int kk = p*16 + kq*4;
            float4 v;
            v.x = src[(kk+0)*64 + bl];
            v.y = src[(kk+1)*64 + bl];
            v.z = src[(kk+2)*64 + bl];
            v.w = src[(kk+3)*64 + bl];
            *(float4*)(dst + kk) = v;
          }
        }
        __syncthreads();

        const float* wsrc; int wstride, kof;
        if (kc < DinL) { wsrc = Wih + (size_t)d*2048*DinL; wstride = DinL; kof = kc; }
        else           { wsrc = Whh + (size_t)d*2048*512;  wstride = 512;  kof = kc - DinL; }
        const float* w0 = wsrc + (size_t)(gq*512 + jbase) * wstride + kof;
        const float* w1 = w0 + wstride;
        const float* w2 = w1 + wstride;
        const float* w3 = w2 + wstride;
        const float* xrow = xh + bq*132;
        #pragma unroll 4
        for (int k4 = 0; k4 < 128; k4 += 4) {
          const float4 xv = *(const float4*)(xrow + k4);
          const float4 wa = *(const float4*)(w0 + k4);
          const float4 wb = *(const float4*)(w1 + k4);
          const float4 wc = *(const float4*)(w2 + k4);
          const float4 wd = *(const float4*)(w3 + k4);
          acc0 += xv.x*wa.x + xv.y*wa.y + xv.z*wa.z + xv.w*wa.w;
          acc1 += xv.x*wb.x + xv.y*wb.y + xv.z*wb.z + xv.w*wb.w;
          acc2 += xv.x*wc.x + xv.y*wc.y + xv.z*wc.z + xv.w*wc.w;
          acc3 += xv.x*wd.x + xv.y*wd.y + xv.z*wd.z + xv.w*wd.w;
        }
      }

      pre[(gq*4+0)*64 + bq] = acc0;
      pre[(gq*4+1)*64 + bq] = acc1;
      pre[(gq*4+2)*64 + bq] = acc2;
      pre[(gq*4+3)*64 + bq] = acc3;
      __syncthreads();
      {
        const float pi = pre[( 0 + jj2)*64 + b2];
        const float pf = pre[( 4 + jj2)*64 + b2];
        const float pg = pre[( 8 + jj2)*64 + b2];
        const float po = pre[(12 + jj2)*64 + b2];
        const float iv = 1.0f/(1.0f + __expf(-pi));
        const float fv = 1.0f/(1.0f + __expf(-pf));
        const float gv = tanhf(pg);
        const float ov = 1.0f/(1.0f + __expf(-po));
        float c = fv*cst[tid] + iv*gv;
        c = fminf(fmaxf(c, -100.0f), 100.0f);
        cst[tid] = c;
        const float h = ov*tanhf(c);
        hb[((cur^1)*2 + d)*32768 + (jbase+jj2)*64 + b2] = h;
        if (layer == 0) {
          h0out[((size_t)t_in*1024 + (size_t)(d*512 + jbase + jj2))*64 + b2] = h;
        } else {
          float* op = outsum + ((size_t)t_in*512 + (size_t)(jbase + jj2))*64 + b2;
          if (s < 256) *op = h; else *op = *op + h;   // first/second visitor; barrier-ordered
        }
      }
      __syncthreads();                                 // drains all wg stores (vmcnt before barrier)
      if (tid == 0)
        __hip_atomic_fetch_add(&ctr[layer*512 + s], 1u, __ATOMIC_ACQ_REL, __HIP_MEMORY_SCOPE_AGENT);
    }
  }
}

// e[b][t] = sum_j out[t][j][b] * Wa[j] + ba
__global__ void __launch_bounds__(256) attn_logits(const float* __restrict__ outsum,
                                                   const float* __restrict__ Wa,
                                                   const float* __restrict__ ba,
                                                   float* __restrict__ e) {
  __shared__ float part[4*64];
  const int t = blockIdx.x;
  const int b = threadIdx.x & 63, jq = threadIdx.x >> 6;
  const float* base = outsum + (size_t)t * 512 * 64;
  float acc = 0.0f;
  for (int j = jq*128; j < jq*128 + 128; ++j)
    acc += base[j*64 + b] * Wa[j];
  part[jq*64 + b] = acc;
  __syncthreads();
  if (threadIdx.x < 64) {
    const int bb = threadIdx.x;
    e[bb*512 + t] = part[0*64+bb] + part[1*64+bb] + part[2*64+bb] + part[3*64+bb] + ba[0];
  }
}

// softmax over t per b; writes attn output (B,T) and transposed (T,B) copy
__global__ void __launch_bounds__(256) attn_softmax(const float* __restrict__ e,
                                                    float* __restrict__ attn,
                                                    float* __restrict__ aT) {
  __shared__ float red[256];
  const int b = blockIdx.x, tid = threadIdx.x;
  const float v0 = e[b*512 + tid];
  const float v1 = e[b*512 + 256 + tid];
  red[tid] = fmaxf(v0, v1);
  __syncthreads();
  for (int st = 128; st; st >>= 1) { if (tid < st) red[tid] = fmaxf(red[tid], red[tid+st]); __syncthreads(); }
  const float M = red[0];
  __syncthreads();
  const float e0 = __expf(v0 - M), e1 = __expf(v1 - M);
  red[tid] = e0 + e1;
  __syncthreads();
  for (int st = 128; st; st >>= 1) { if (tid < st) red[tid] += red[tid+st]; __syncthreads(); }
  const float inv = 1.0f / red[0];
  const float a0 = e0*inv, a1 = e1*inv;
  attn[b*512 + tid]       = a0;
  attn[b*512 + 256 + tid] = a1;
  aT[tid*64 + b]       = a0;
  aT[(256+tid)*64 + b] = a1;
}

// pooled[j][b] = sum_t aT[t][b] * out[t][j][b]
__global__ void __launch_bounds__(256) attn_pool(const float* __restrict__ outsum,
                                                 const float* __restrict__ aT,
                                                 float* __restrict__ pooled) {
  const int tid = threadIdx.x;
  const int b = tid & 63, jj = tid >> 6;
  const int j = blockIdx.x*4 + jj;
  float acc = 0.0f;
  #pragma unroll 4
  for (int t = 0; t < 512; ++t)
    acc += aT[t*64 + b] * outsum[((size_t)t*512 + j)*64 + b];
  pooled[j*64 + b] = acc;
}

// pred[b][o] = pooled[:,b] . Wo[o,:] + bo[o]
__global__ void __launch_bounds__(128) pred_kern(const float* __restrict__ pooled,
                                                 const float* __restrict__ Wo,
                                                 const float* __restrict__ bo,
                                                 float* __restrict__ out) {
  const int b = blockIdx.x, o = threadIdx.x;
  float acc = bo[o];
  const float* wr = Wo + o*512;
  #pragma unroll 4
  for (int j = 0; j < 512; j += 4) {
    const float4 w = *(const float4*)(wr + j);
    acc += w.x*pooled[(j+0)*64 + b] + w.y*pooled[(j+1)*64 + b]
         + w.z*pooled[(j+2)*64 + b] + w.w*pooled[(j+3)*64 + b];
  }
  out[b*128 + o] = acc;
}

extern "C" void kernel_launch(void* const* d_in, const int* in_sizes, int n_in,
                              void* d_out, int out_size, void* d_ws, size_t ws_size,
                              hipStream_t stream) {
  (void)in_sizes; (void)n_in; (void)out_size; (void)ws_size;
  const float* x    = (const float*)d_in[0];
  const float* Wih0 = (const float*)d_in[1];
  const float* Whh0 = (const float*)d_in[2];
  const float* b0   = (const float*)d_in[3];
  const float* Wih1 = (const float*)d_in[4];
  const float* Whh1 = (const float*)d_in[5];
  const float* b1   = (const float*)d_in[6];
  const float* Wa   = (const float*)d_in[7];
  const float* ba   = (const float*)d_in[8];
  const float* Wo   = (const float*)d_in[9];
  const float* bo   = (const float*)d_in[10];
  float* out = (float*)d_out;
  float* ws  = (float*)d_ws;

  // zero hidden pingpong buffers + step counters (contiguous region)
  hipMemsetAsync(ws + OFF_HBUF, 0, (LEN_HBUF + LEN_CTR) * sizeof(float), stream);

  void* args[] = { (void*)&x, (void*)&Wih0, (void*)&Whh0, (void*)&b0,
                   (void*)&Wih1, (void*)&Whh1, (void*)&b1, (void*)&ws };
  hipLaunchCooperativeKernel((void*)lstm_coop, dim3(NWG), dim3(256), args, 0, stream);

  attn_logits <<<512, 256, 0, stream>>>(ws + OFF_OUT, Wa, ba, ws + OFF_E);
  attn_softmax<<< 64, 256, 0, stream>>>(ws + OFF_E, out + 8192, ws + OFF_AT);
  attn_pool   <<<128, 256, 0, stream>>>(ws + OFF_OUT, ws + OFF_AT, ws + OFF_POOL);
  pred_kern   <<< 64, 128, 0, stream>>>(ws + OFF_POOL, Wo, bo, out);
}

// Round 2
// 27134.372 us; speedup vs baseline: 5.6008x; 5.6008x over previous
//
#include <hip/hip_runtime.h>
#include <cstdint>
#include <cstddef>

#define TT 512
#define NWG 256

// Workspace layout (float offsets)
#define OFF_H0OUT 0ul
#define LEN_H0OUT (512ul*1024ul*64ul)            /* layer0 output, (T,1024,B) */
#define OFF_OUT   (OFF_H0OUT + LEN_H0OUT)
#define LEN_OUT   (512ul*512ul*64ul)             /* layer1 fwd+bwd sum, (T,512,B) */
#define OFF_HBUF  (OFF_OUT + LEN_OUT)
#define LEN_HBUF  (2ul*2ul*2ul*512ul*64ul)       /* [layer][pingpong][dir][j][b] */
#define OFF_CTR   (OFF_HBUF + LEN_HBUF)
#define LEN_CTR   2048ul                          /* [layer*2+dir][step] u32 counters */
#define OFF_E     (OFF_CTR + LEN_CTR)
#define LEN_E     (64ul*512ul)
#define OFF_AT    (OFF_E + LEN_E)
#define LEN_AT    (512ul*64ul)
#define OFF_POOL  (OFF_AT + LEN_AT)
#define LEN_POOL  (512ul*64ul)

#define WLDS_FLOATS (16*1536)
#define XBUF_OFF    WLDS_FLOATS
#define DYN_LDS_BYTES ((WLDS_FLOATS + 8192)*4)   /* 128 KB */

// Persistent cooperative kernel, 256 wgs x 256 thr (1 wg/CU).
// wg -> dir d = wg>>7, j-columns jbase..jbase+4 (16 gate rows, lr = g*4+jj).
// Weights for the wg's 16 rows live in LDS (layer1: 96 KB). Per-thread 8x8
// register tile (rows x batches), 16-way k-split (kg), LDS tree reduction.
__global__ void __launch_bounds__(256, 1) lstm_coop(
    const float* __restrict__ x,
    const float* __restrict__ Wih0, const float* __restrict__ Whh0, const float* __restrict__ b0,
    const float* __restrict__ Wih1, const float* __restrict__ Whh1, const float* __restrict__ b1,
    float* __restrict__ ws)
{
  extern __shared__ float lds[];
  float* wlds = lds;                 // [16][K] row-major, lr = g*4+jj
  float* xbuf = lds + XBUF_OFF;      // [128][64] chunk of x, batch-rotated per k8-block
  __shared__ float cst[256];         // cell state [jj][b]

  float* h0out  = ws + OFF_H0OUT;
  float* outsum = ws + OFF_OUT;
  float* hbuf   = ws + OFF_HBUF;
  unsigned* ctr = (unsigned*)(ws + OFF_CTR);

  const int tid = threadIdx.x;
  const int wg  = blockIdx.x;
  const int d     = wg >> 7;
  const int jbase = (wg & 127) << 2;

  // main-loop thread map: wave = {kg x4, bg x8, rg x2}
  const int kg = tid >> 4;          // 16 k-groups (8 k each per 128-chunk)
  const int bg = (tid >> 1) & 7;    // 8 batch-groups (8 batches)
  const int rg = tid & 1;           // 2 row-groups (8 rows)
  const int lrb = rg << 3;
  // epilogue map
  const int b2  = tid & 63;
  const int jj2 = tid >> 6;

  for (int layer = 0; layer < 2; ++layer) {
    const int DinL = layer ? 1024 : 256;
    const int K    = DinL + 512;
    const int nchunk = K >> 7;
    const float* Wih  = layer ? Wih1 : Wih0;
    const float* Whh  = layer ? Whh1 : Whh0;
    const float* bias = layer ? b1 : b0;
    float* hb = hbuf + (size_t)layer * 131072;

    // ---- stage this wg's 16 weight rows into LDS (once per layer) ----
    for (int lr = 0; lr < 16; ++lr) {
      const int row = (lr >> 2)*512 + jbase + (lr & 3);     // g*512 + jbase + jj
      const float* srcw = Wih + ((size_t)d*2048 + row) * DinL;
      float* dstw = wlds + lr*K;
      for (int k = tid*4; k < DinL; k += 1024)
        *(float4*)(dstw + k) = *(const float4*)(srcw + k);
      const float* srch = Whh + ((size_t)d*2048 + row) * 512;
      for (int k = tid*4; k < 512; k += 1024)
        *(float4*)(dstw + DinL + k) = *(const float4*)(srch + k);
    }

    // per-thread epilogue biases (column jbase+jj2, 4 gates)
    const float bi  = bias[d*2048 +        jbase + jj2];
    const float bf  = bias[d*2048 +  512 + jbase + jj2];
    const float bgg = bias[d*2048 + 1024 + jbase + jj2];
    const float bo  = bias[d*2048 + 1536 + jbase + jj2];

    cst[tid] = 0.0f;

    if (layer == 1 && tid == 0) {   // gate: layer0 fully done (both dirs)
      while (__hip_atomic_load(&ctr[511],     __ATOMIC_ACQUIRE, __HIP_MEMORY_SCOPE_AGENT) < 128u)
        __builtin_amdgcn_s_sleep(1);
      while (__hip_atomic_load(&ctr[512+511], __ATOMIC_ACQUIRE, __HIP_MEMORY_SCOPE_AGENT) < 128u)
        __builtin_amdgcn_s_sleep(1);
    }
    __syncthreads();   // weights staged + cst init + gate

    const unsigned cbase = (unsigned)(layer*2 + d) * 512u;
    const int col0 = ((bg << 3) +     (kg << 2)) & 63;
    const int col1 = ((bg << 3) + 4 + (kg << 2)) & 63;

    for (int s = 0; s < TT; ++s) {
      const int t_in = d ? (TT - 1 - s) : s;
      if (s > 0) {
        if (tid == 0) {
          const unsigned* p = &ctr[cbase + (unsigned)s - 1u];
          while (__hip_atomic_load(p, __ATOMIC_ACQUIRE, __HIP_MEMORY_SCOPE_AGENT) < 128u)
            __builtin_amdgcn_s_sleep(1);
        }
        __syncthreads();
      }
      const float* hin = hb + ((s & 1)*2 + d)*32768;

      float acc[8][8];
      #pragma unroll
      for (int i = 0; i < 8; ++i)
        #pragma unroll
        for (int j = 0; j < 8; ++j) acc[i][j] = 0.0f;

      for (int ch = 0; ch < nchunk; ++ch) {
        const int kc = ch << 7;
        __syncthreads();                       // WAR on xbuf
        if (layer == 0 && ch < 2) {
          // transpose-stage from x (T,B,256): thread (bb=tid>>2, kq=tid&3)
          const int bb = tid >> 2, kq = tid & 3;
          const float* src = x + ((size_t)t_in*64 + bb)*256 + kc + kq*32;
          #pragma unroll
          for (int i2 = 0; i2 < 8; ++i2) {
            const float4 v = *(const float4*)(src + i2*4);
            const int k0  = kq*32 + i2*4;
            const int cc  = (bb + (((k0 >> 3) << 2) & 63)) & 63;
            xbuf[(k0+0)*64 + cc] = v.x;
            xbuf[(k0+1)*64 + cc] = v.y;
            xbuf[(k0+2)*64 + cc] = v.z;
            xbuf[(k0+3)*64 + cc] = v.w;
          }
        } else {
          // straight copy from [k][b] source (h0out slice or hidden pingpong)
          const float* src = (kc < DinL)
              ? (h0out + (size_t)t_in*65536 + (size_t)kc*64)   // layer1 only reaches here for kc<DinL
              : (hin + (size_t)(kc - DinL)*64);
          if (layer == 0) src = hin + (size_t)(kc - 256)*64;   // layer0 ch>=2 is always h
          #pragma unroll
          for (int i2 = 0; i2 < 8; ++i2) {
            const int f4 = i2*256 + tid;
            const float4 v = *(const float4*)(src + (size_t)f4*4);
            const int k   = f4 >> 4;
            const int cb4 = (f4 & 15) << 2;
            const int cc  = (cb4 + (((k >> 3) << 2) & 63)) & 63;
            *(float4*)(xbuf + k*64 + cc) = v;
          }
        }
        __syncthreads();

        const float* wrow = wlds + lrb*K + kc + (kg << 3);
        const float* xk   = xbuf + (kg << 3)*64;
        #pragma unroll
        for (int k4 = 0; k4 < 2; ++k4) {
          float4 wv[8];
          #pragma unroll
          for (int i = 0; i < 8; ++i) wv[i] = *(const float4*)(wrow + i*K + k4*4);
          float4 xv0[4], xv1[4];
          #pragma unroll
          for (int kk = 0; kk < 4; ++kk) {
            xv0[kk] = *(const float4*)(xk + (k4*4 + kk)*64 + col0);
            xv1[kk] = *(const float4*)(xk + (k4*4 + kk)*64 + col1);
          }
          #define OUTER(i, WC, XA, XB) \
            acc[i][0] += (WC)*(XA).x; acc[i][1] += (WC)*(XA).y; \
            acc[i][2] += (WC)*(XA).z; acc[i][3] += (WC)*(XA).w; \
            acc[i][4] += (WC)*(XB).x; acc[i][5] += (WC)*(XB).y; \
            acc[i][6] += (WC)*(XB).z; acc[i][7] += (WC)*(XB).w;
          #pragma unroll
          for (int i = 0; i < 8; ++i) {
            OUTER(i, wv[i].x, xv0[0], xv1[0]);
            OUTER(i, wv[i].y, xv0[1], xv1[1]);
            OUTER(i, wv[i].z, xv0[2], xv1[2]);
            OUTER(i, wv[i].w, xv0[3], xv1[3]);
          }
          #undef OUTER
        }
      }

      // ---- cross-kg tree reduction through xbuf ----
      #pragma unroll
      for (int half = 8; half >= 1; half >>= 1) {
        __syncthreads();
        if (kg >= half && kg < 2*half) {
          const int blk = kg - half;
          const int rot2 = (blk << 2) & 63;
          float* dst = xbuf + blk*1024 + lrb*64;
          #pragma unroll
          for (int i = 0; i < 8; ++i) {
            *(float4*)(dst + i*64 + (((bg<<3)     + rot2) & 63)) =
                make_float4(acc[i][0], acc[i][1], acc[i][2], acc[i][3]);
            *(float4*)(dst + i*64 + (((bg<<3) + 4 + rot2) & 63)) =
                make_float4(acc[i][4], acc[i][5], acc[i][6], acc[i][7]);
          }
        }
        __syncthreads();
        if (kg < half) {
          const int rot2 = (kg << 2) & 63;
          const float* srcp = xbuf + kg*1024 + lrb*64;
          #pragma unroll
          for (int i = 0; i < 8; ++i) {
            const float4 v0 = *(const float4*)(srcp + i*64 + (((bg<<3)     + rot2) & 63));
            const float4 v1 = *(const float4*)(srcp + i*64 + (((bg<<3) + 4 + rot2) & 63));
            acc[i][0] += v0.x; acc[i][1] += v0.y; acc[i][2] += v0.z; acc[i][3] += v0.w;
            acc[i][4] += v1.x; acc[i][5] += v1.y; acc[i][6] += v1.z; acc[i][7] += v1.w;
          }
        }
      }
      __syncthreads();
      if (kg == 0) {   // kg0 threads hold full preacts for all 16 rows
        float* dst = xbuf + lrb*64 + (bg << 3);
        #pragma unroll
        for (int i = 0; i < 8; ++i) {
          *(float4*)(dst + i*64)     = make_float4(acc[i][0], acc[i][1], acc[i][2], acc[i][3]);
          *(float4*)(dst + i*64 + 4) = make_float4(acc[i][4], acc[i][5], acc[i][6], acc[i][7]);
        }
      }
      __syncthreads();

      // ---- epilogue: gates, cell state, h writes ----
      {
        const float pi = xbuf[( 0 + jj2)*64 + b2] + bi;
        const float pf = xbuf[( 4 + jj2)*64 + b2] + bf;
        const float pg = xbuf[( 8 + jj2)*64 + b2] + bgg;
        const float po = xbuf[(12 + jj2)*64 + b2] + bo;
        const float iv = 1.0f/(1.0f + __expf(-pi));
        const float fv = 1.0f/(1.0f + __expf(-pf));
        const float gv = tanhf(pg);
        const float ov = 1.0f/(1.0f + __expf(-po));
        float c = fv*cst[tid] + iv*gv;
        c = fminf(fmaxf(c, -100.0f), 100.0f);
        cst[tid] = c;
        const float h = ov*tanhf(c);
        hb[(((s & 1) ^ 1)*2 + d)*32768 + (jbase + jj2)*64 + b2] = h;
        if (layer == 0) {
          h0out[(size_t)t_in*65536 + (size_t)(d*512 + jbase + jj2)*64 + b2] = h;
        } else {
          atomicAdd(&outsum[(size_t)t_in*32768 + (size_t)(jbase + jj2)*64 + b2], h);
        }
      }
      __syncthreads();   // drain stores before release
      if (tid == 0)
        __hip_atomic_fetch_add(&ctr[cbase + (unsigned)s], 1u, __ATOMIC_ACQ_REL, __HIP_MEMORY_SCOPE_AGENT);
    }
  }
}

// e[b][t] = sum_j out[t][j][b] * Wa[j] + ba
__global__ void __launch_bounds__(256) attn_logits(const float* __restrict__ outsum,
                                                   const float* __restrict__ Wa,
                                                   const float* __restrict__ ba,
                                                   float* __restrict__ e) {
  __shared__ float part[4*64];
  const int t = blockIdx.x;
  const int b = threadIdx.x & 63, jq = threadIdx.x >> 6;
  const float* base = outsum + (size_t)t * 512 * 64;
  float acc = 0.0f;
  for (int j = jq*128; j < jq*128 + 128; ++j)
    acc += base[j*64 + b] * Wa[j];
  part[jq*64 + b] = acc;
  __syncthreads();
  if (threadIdx.x < 64) {
    const int bb = threadIdx.x;
    e[bb*512 + t] = part[0*64+bb] + part[1*64+bb] + part[2*64+bb] + part[3*64+bb] + ba[0];
  }
}

__global__ void __launch_bounds__(256) attn_softmax(const float* __restrict__ e,
                                                    float* __restrict__ attn,
                                                    float* __restrict__ aT) {
  __shared__ float red[256];
  const int b = blockIdx.x, tid = threadIdx.x;
  const float v0 = e[b*512 + tid];
  const float v1 = e[b*512 + 256 + tid];
  red[tid] = fmaxf(v0, v1);
  __syncthreads();
  for (int st = 128; st; st >>= 1) { if (tid < st) red[tid] = fmaxf(red[tid], red[tid+st]); __syncthreads(); }
  const float M = red[0];
  __syncthreads();
  const float e0 = __expf(v0 - M), e1 = __expf(v1 - M);
  red[tid] = e0 + e1;
  __syncthreads();
  for (int st = 128; st; st >>= 1) { if (tid < st) red[tid] += red[tid+st]; __syncthreads(); }
  const float inv = 1.0f / red[0];
  const float a0 = e0*inv, a1 = e1*inv;
  attn[b*512 + tid]       = a0;
  attn[b*512 + 256 + tid] = a1;
  aT[tid*64 + b]       = a0;
  aT[(256+tid)*64 + b] = a1;
}

__global__ void __launch_bounds__(256) attn_pool(const float* __restrict__ outsum,
                                                 const float* __restrict__ aT,
                                                 float* __restrict__ pooled) {
  const int tid = threadIdx.x;
  const int b = tid & 63, jj = tid >> 6;
  const int j = blockIdx.x*4 + jj;
  float acc = 0.0f;
  #pragma unroll 4
  for (int t = 0; t < 512; ++t)
    acc += aT[t*64 + b] * outsum[((size_t)t*512 + j)*64 + b];
  pooled[j*64 + b] = acc;
}

__global__ void __launch_bounds__(128) pred_kern(const float* __restrict__ pooled,
                                                 const float* __restrict__ Wo,
                                                 const float* __restrict__ bo,
                                                 float* __restrict__ out) {
  const int b = blockIdx.x, o = threadIdx.x;
  float acc = bo[o];
  const float* wr = Wo + o*512;
  #pragma unroll 4
  for (int j = 0; j < 512; j += 4) {
    const float4 w = *(const float4*)(wr + j);
    acc += w.x*pooled[(j+0)*64 + b] + w.y*pooled[(j+1)*64 + b]
         + w.z*pooled[(j+2)*64 + b] + w.w*pooled[(j+3)*64 + b];
  }
  out[b*128 + o] = acc;
}

extern "C" void kernel_launch(void* const* d_in, const int* in_sizes, int n_in,
                              void* d_out, int out_size, void* d_ws, size_t ws_size,
                              hipStream_t stream) {
  (void)in_sizes; (void)n_in; (void)out_size; (void)ws_size;
  const float* x    = (const float*)d_in[0];
  const float* Wih0 = (const float*)d_in[1];
  const float* Whh0 = (const float*)d_in[2];
  const float* b0   = (const float*)d_in[3];
  const float* Wih1 = (const float*)d_in[4];
  const float* Whh1 = (const float*)d_in[5];
  const float* b1   = (const float*)d_in[6];
  const float* Wa   = (const float*)d_in[7];
  const float* ba   = (const float*)d_in[8];
  const float* Wo   = (const float*)d_in[9];
  const float* bo   = (const float*)d_in[10];
  float* out = (float*)d_out;
  float* ws  = (float*)d_ws;

  static int attr_set = 0;   // idempotent attribute; safe under capture (host-side, not a stream op)
  hipFuncSetAttribute((const void*)lstm_coop, hipFuncAttributeMaxDynamicSharedMemorySize, DYN_LDS_BYTES);
  (void)attr_set;

  // zero: hidden pingpong + counters, and the atomically-accumulated output
  hipMemsetAsync(ws + OFF_HBUF, 0, (LEN_HBUF + LEN_CTR) * sizeof(float), stream);
  hipMemsetAsync(ws + OFF_OUT, 0, LEN_OUT * sizeof(float), stream);

  void* args[] = { (void*)&x, (void*)&Wih0, (void*)&Whh0, (void*)&b0,
                   (void*)&Wih1, (void*)&Whh1, (void*)&b1, (void*)&ws };
  hipLaunchCooperativeKernel((void*)lstm_coop, dim3(NWG), dim3(256), args, DYN_LDS_BYTES, stream);

  attn_logits <<<512, 256, 0, stream>>>(ws + OFF_OUT, Wa, ba, ws + OFF_E);
  attn_softmax<<< 64, 256, 0, stream>>>(ws + OFF_E, out + 8192, ws + OFF_AT);
  attn_pool   <<<128, 256, 0, stream>>>(ws + OFF_OUT, ws + OFF_AT, ws + OFF_POOL);
  pred_kern   <<< 64, 128, 0, stream>>>(ws + OFF_POOL, Wo, bo, out);
}